// Round 7
// baseline (898.625 us; speedup 1.0000x reference)
//
#include <hip/hip_runtime.h>
#include <hip/hip_cooperative_groups.h>

namespace cg = cooperative_groups;

using u16 = unsigned short;
typedef __bf16 bf16x8 __attribute__((ext_vector_type(8)));
typedef float floatx4 __attribute__((ext_vector_type(4)));

// ---------- helpers ----------
__device__ __forceinline__ u16 f2bf(float f) {
    union { float f; unsigned u; } v; v.f = f;
    unsigned r = v.u + 0x7fffu + ((v.u >> 16) & 1u);   // RNE
    return (u16)(r >> 16);
}

__device__ __forceinline__ void gld16(const void* g, void* l) {
    __builtin_amdgcn_global_load_lds(
        (const __attribute__((address_space(1))) void*)g,
        (__attribute__((address_space(3))) void*)l, 16, 0, 0);
}

__device__ __forceinline__ void cvt4(const float* __restrict__ src,
                                     u16* __restrict__ dst, int i) {
    float4 v = *(const float4*)(src + i);
    ushort4 o;
    o.x = f2bf(v.x); o.y = f2bf(v.y); o.z = f2bf(v.z); o.w = f2bf(v.w);
    *(ushort4*)(dst + i) = o;
}

// ============================================================================
// Cooperative single-kernel path. Phase bodies = round-5 verified kernels.
// ============================================================================
__global__ __launch_bounds__(256, 3) void mega_k(
    const float* __restrict__ x, const float* __restrict__ te,
    const float* __restrict__ Wqkv, const float* __restrict__ bqkv,
    const float* __restrict__ Wt, const float* __restrict__ bt,
    const float* __restrict__ Wo, const float* __restrict__ bo,
    const float* __restrict__ btab, float* __restrict__ out,
    char* __restrict__ ws)
{
    u16*   xbf    = (u16*)(ws);                  // x bf16, later reused as aout
    u16*   qkvbf  = (u16*)(ws + 67108864);
    u16*   wqkvbf = (u16*)(ws + 268435456);
    u16*   wobf   = (u16*)(ws + 270008320);
    float* qkvt   = (float*)(ws + 270532608);
    float* biasf  = (float*)(ws + 270630912);

    __shared__ __align__(16) u16 smem[18432];    // 36,864 B union
    u16* lA = smem;                              // gemm: [128*32]
    u16* lB = smem + 4096;

    cg::grid_group grid = cg::this_grid();
    const int tid = threadIdx.x;
    const int lane = tid & 63, wv = tid >> 6;
    const int ln = lane & 15, quad = lane >> 4;
    const int nb = gridDim.x;

    // ================= P0: prep =================
    for (int b = blockIdx.x; b < 9344; b += nb) {
        if (b < 768) {
            cvt4(Wqkv, wqkvbf, b * 1024 + tid * 4);
        } else if (b < 1024) {
            cvt4(Wo, wobf, (b - 768) * 1024 + tid * 4);
        } else if (b < 1120) {
            const int bb = b - 1024;
            const int batch = bb / 6;
            const int c = (bb % 6) * 256 + tid;
            const float4* a4 = (const float4*)(te + batch * 512);
            const float4* w4 = (const float4*)(Wt + (size_t)c * 512);
            float s = 0.f;
            for (int i = 0; i < 128; ++i) {
                float4 av = a4[i], wvv = w4[i];
                s += av.x * wvv.x + av.y * wvv.y + av.z * wvv.z + av.w * wvv.w;
            }
            qkvt[batch * 1536 + c] = s + bt[c];
        } else if (b < 1152) {
            const int e0 = (b - 1120) * 1024 + tid;
            for (int k = 0; k < 4; ++k) {
                int e = e0 + k * 256;
                int h = e >> 12, rc = e & 4095, row = rc >> 6, col = rc & 63;
                int idx = ((row >> 3) - (col >> 3) + 7) * 15 + ((row & 7) - (col & 7) + 7);
                biasf[e] = btab[idx * 8 + h];
            }
        } else {
            const int base = (b - 1152) * 4096 + tid * 4;
            for (int k = 0; k < 4; ++k) cvt4(x, xbf, base + k * 1024);
        }
    }

    __threadfence();   // cross-XCD release insurance
    grid.sync();
    __threadfence();   // acquire insurance

    // ================= P1: qkv = x @ Wqkv^T + bqkv + qkv_t =================
    {
        const int wm = (wv & 1) * 64, wn = (wv >> 1) * 64;
        const int srow = tid >> 2, scb = tid & 3;
        u16* la0 = &lA[tid * 8];
        u16* la1 = &lA[2048 + tid * 8];
        u16* lb0 = &lB[tid * 8];
        u16* lb1 = &lB[2048 + tid * 8];

        for (int v = blockIdx.x; v < 6144; v += nb) {
            const int wgid = (v & 7) * 768 + (v >> 3);   // 6144 % 8 == 0
            const int tm = wgid / 12, tn = wgid % 12;

            floatx4 acc[4][4];
#pragma unroll
            for (int i = 0; i < 4; ++i)
#pragma unroll
                for (int j = 0; j < 4; ++j) acc[i][j] = (floatx4){0.f, 0.f, 0.f, 0.f};

            const u16* ag = xbf + (size_t)(tm * 128 + srow) * 512 + scb * 8;
            const u16* bg = wqkvbf + (size_t)(tn * 128 + srow) * 512 + scb * 8;

            for (int k0 = 0; k0 < 512; k0 += 32) {
                __syncthreads();
                gld16(ag + k0, la0);
                gld16(ag + 64 * 512 + k0, la1);
                gld16(bg + k0, lb0);
                gld16(bg + 64 * 512 + k0, lb1);
                __syncthreads();          // drains vmcnt: LDS tiles ready
                bf16x8 af[4], bf[4];
#pragma unroll
                for (int mt = 0; mt < 4; ++mt)
                    af[mt] = *(const bf16x8*)&lA[(wm + mt * 16 + ln) * 32 + quad * 8];
#pragma unroll
                for (int nt = 0; nt < 4; ++nt)
                    bf[nt] = *(const bf16x8*)&lB[(wn + nt * 16 + ln) * 32 + quad * 8];
#pragma unroll
                for (int mt = 0; mt < 4; ++mt)
#pragma unroll
                    for (int nt = 0; nt < 4; ++nt)
                        acc[mt][nt] = __builtin_amdgcn_mfma_f32_16x16x32_bf16(
                            af[mt], bf[nt], acc[mt][nt], 0, 0, 0);
            }
            __syncthreads();

            const float* qt = qkvt + (tm >> 5) * 1536;
#pragma unroll
            for (int nt = 0; nt < 4; ++nt) {
                const int col = tn * 128 + wn + nt * 16 + ln;
                const float add = bqkv[col] + qt[col];
#pragma unroll
                for (int mt = 0; mt < 4; ++mt) {
                    const int row0 = tm * 128 + wm + mt * 16 + quad * 4;
#pragma unroll
                    for (int r = 0; r < 4; ++r)
                        qkvbf[(size_t)(row0 + r) * 1536 + col] = f2bf(acc[mt][nt][r] + add);
                }
            }
        }
    }

    __threadfence();
    grid.sync();
    __threadfence();

    // ================= P2: attention (1 wave per (window,head)) =================
    {
        u16* buf = smem + wv * 4608;             // 64*72 per wave
        for (int v = blockIdx.x; v < 2048; v += nb) {
            const int pair = v * 4 + wv;
            const int w = pair >> 3, h = pair & 7;
            const int bb = w >> 6, nh = (w >> 3) & 7, nw = w & 7;
            const int tbase = bb * 4096 + nh * 512 + nw * 8;

            {
                const int wj = lane >> 3;
                const int d0 = (lane & 7) * 8;
#pragma unroll
                for (int i = 0; i < 8; ++i) {
                    const int t = tbase + i * 64 + wj;
                    union { bf16x8 v; u16 u[8]; } cv;
                    cv.v = *(const bf16x8*)(qkvbf + (size_t)t * 1536 + 1024 + h * 64 + d0);
                    const int n = i * 8 + wj;
#pragma unroll
                    for (int j = 0; j < 8; ++j) buf[(d0 + j) * 72 + n] = cv.u[j];
                }
            }

            bf16x8 vtf[4][2];
#pragma unroll
            for (int dt = 0; dt < 4; ++dt) {
                const u16* vr = &buf[(dt * 16 + ln) * 72 + quad * 8];
                vtf[dt][0] = *(const bf16x8*)vr;
                vtf[dt][1] = *(const bf16x8*)(vr + 32);
            }

            bf16x8 kf[4][2];
#pragma unroll
            for (int nt = 0; nt < 4; ++nt) {
                const int n = nt * 16 + ln;
                const int t = tbase + (n >> 3) * 64 + (n & 7);
                const u16* kr = qkvbf + (size_t)t * 1536 + 512 + h * 64 + quad * 8;
                kf[nt][0] = *(const bf16x8*)kr;
                kf[nt][1] = *(const bf16x8*)(kr + 32);
            }

#pragma unroll
            for (int mt = 0; mt < 4; ++mt) {
                const int m = mt * 16 + ln;
                const int t = tbase + (m >> 3) * 64 + (m & 7);
                const u16* qr = qkvbf + (size_t)t * 1536 + h * 64 + quad * 8;
                const bf16x8 qf0 = *(const bf16x8*)qr;
                const bf16x8 qf1 = *(const bf16x8*)(qr + 32);
                floatx4 s[4];
                __builtin_amdgcn_s_setprio(1);
#pragma unroll
                for (int nt = 0; nt < 4; ++nt) {
                    s[nt] = (floatx4){0.f, 0.f, 0.f, 0.f};
                    s[nt] = __builtin_amdgcn_mfma_f32_16x16x32_bf16(qf0, kf[nt][0], s[nt], 0, 0, 0);
                    s[nt] = __builtin_amdgcn_mfma_f32_16x16x32_bf16(qf1, kf[nt][1], s[nt], 0, 0, 0);
                }
                __builtin_amdgcn_s_setprio(0);
                float z[4][4];
                const float* bptr = biasf + h * 4096 + (mt * 16 + quad * 4) * 64 + ln;
#pragma unroll
                for (int nt = 0; nt < 4; ++nt)
#pragma unroll
                    for (int r = 0; r < 4; ++r)
                        z[nt][r] = s[nt][r] * 0.125f + bptr[r * 64 + nt * 16];
                float pmax[4], prcp[4];
#pragma unroll
                for (int r = 0; r < 4; ++r) {
                    float vv = fmaxf(fmaxf(z[0][r], z[1][r]), fmaxf(z[2][r], z[3][r]));
                    vv = fmaxf(vv, __shfl_xor(vv, 1));
                    vv = fmaxf(vv, __shfl_xor(vv, 2));
                    vv = fmaxf(vv, __shfl_xor(vv, 4));
                    vv = fmaxf(vv, __shfl_xor(vv, 8));
                    pmax[r] = vv;
                }
#pragma unroll
                for (int nt = 0; nt < 4; ++nt)
#pragma unroll
                    for (int r = 0; r < 4; ++r)
                        z[nt][r] = __expf(z[nt][r] - pmax[r]);
#pragma unroll
                for (int r = 0; r < 4; ++r) {
                    float vv = z[0][r] + z[1][r] + z[2][r] + z[3][r];
                    vv += __shfl_xor(vv, 1);
                    vv += __shfl_xor(vv, 2);
                    vv += __shfl_xor(vv, 4);
                    vv += __shfl_xor(vv, 8);
                    prcp[r] = __builtin_amdgcn_rcpf(vv);
                }
#pragma unroll
                for (int nt = 0; nt < 4; ++nt)
#pragma unroll
                    for (int r = 0; r < 4; ++r)
                        buf[(mt * 16 + quad * 4 + r) * 72 + nt * 16 + ln] =
                            f2bf(z[nt][r] * prcp[r]);
            }

#pragma unroll
            for (int mt = 0; mt < 4; ++mt) {
                const u16* pr = &buf[(mt * 16 + ln) * 72 + quad * 8];
                const bf16x8 pf0 = *(const bf16x8*)pr;
                const bf16x8 pf1 = *(const bf16x8*)(pr + 32);
#pragma unroll
                for (int dt = 0; dt < 4; ++dt) {
                    floatx4 o = (floatx4){0.f, 0.f, 0.f, 0.f};
                    __builtin_amdgcn_s_setprio(1);
                    o = __builtin_amdgcn_mfma_f32_16x16x32_bf16(pf0, vtf[dt][0], o, 0, 0, 0);
                    o = __builtin_amdgcn_mfma_f32_16x16x32_bf16(pf1, vtf[dt][1], o, 0, 0, 0);
                    __builtin_amdgcn_s_setprio(0);
                    const size_t rbase =
                        (size_t)(w * 64 + mt * 16 + quad * 4) * 512 + h * 64 + dt * 16 + ln;
#pragma unroll
                    for (int r = 0; r < 4; ++r)
                        xbf[rbase + (size_t)r * 512] = f2bf(o[r]);
                }
            }
        }
    }

    __threadfence();
    grid.sync();
    __threadfence();

    // ================= P3: out = attn @ Wo^T + bo =================
    {
        const int wm = (wv & 1) * 64, wn = (wv >> 1) * 64;
        const int srow = tid >> 2, scb = tid & 3;
        u16* la0 = &lA[tid * 8];
        u16* la1 = &lA[2048 + tid * 8];
        u16* lb0 = &lB[tid * 8];
        u16* lb1 = &lB[2048 + tid * 8];

        for (int v = blockIdx.x; v < 2048; v += nb) {
            const int wgid = (v & 7) * 256 + (v >> 3);   // 2048 % 8 == 0
            const int tm = wgid >> 2, tn = wgid & 3;

            floatx4 acc[4][4];
#pragma unroll
            for (int i = 0; i < 4; ++i)
#pragma unroll
                for (int j = 0; j < 4; ++j) acc[i][j] = (floatx4){0.f, 0.f, 0.f, 0.f};

            const u16* ag = xbf + (size_t)(tm * 128 + srow) * 512 + scb * 8;
            const u16* bg = wobf + (size_t)(tn * 128 + srow) * 512 + scb * 8;

            for (int k0 = 0; k0 < 512; k0 += 32) {
                __syncthreads();
                gld16(ag + k0, la0);
                gld16(ag + 64 * 512 + k0, la1);
                gld16(bg + k0, lb0);
                gld16(bg + 64 * 512 + k0, lb1);
                __syncthreads();
                bf16x8 af[4], bf[4];
#pragma unroll
                for (int mt = 0; mt < 4; ++mt)
                    af[mt] = *(const bf16x8*)&lA[(wm + mt * 16 + ln) * 32 + quad * 8];
#pragma unroll
                for (int nt = 0; nt < 4; ++nt)
                    bf[nt] = *(const bf16x8*)&lB[(wn + nt * 16 + ln) * 32 + quad * 8];
#pragma unroll
                for (int mt = 0; mt < 4; ++mt)
#pragma unroll
                    for (int nt = 0; nt < 4; ++nt)
                        acc[mt][nt] = __builtin_amdgcn_mfma_f32_16x16x32_bf16(
                            af[mt], bf[nt], acc[mt][nt], 0, 0, 0);
            }
            __syncthreads();

#pragma unroll
            for (int nt = 0; nt < 4; ++nt) {
                const int col = tn * 128 + wn + nt * 16 + ln;
                const float add = bo[col];
#pragma unroll
                for (int mt = 0; mt < 4; ++mt) {
                    const int row0 = tm * 128 + wm + mt * 16 + quad * 4;
#pragma unroll
                    for (int r = 0; r < 4; ++r)
                        out[(size_t)(row0 + r) * 512 + col] = acc[mt][nt][r] + add;
                }
            }
        }
    }
}

// ============================================================================
// Fallback path: exact round-5 verified kernels.
// ============================================================================
__global__ __launch_bounds__(256) void prep_k(
    const float* __restrict__ x, const float* __restrict__ Wqkv,
    const float* __restrict__ Wo, const float* __restrict__ te,
    const float* __restrict__ Wt, const float* __restrict__ bt,
    const float* __restrict__ btab,
    u16* __restrict__ xbf, u16* __restrict__ wqkvbf, u16* __restrict__ wobf,
    float* __restrict__ qkvt, float* __restrict__ biasf)
{
    const int b = blockIdx.x, tid = threadIdx.x;
    if (b < 768) {
        cvt4(Wqkv, wqkvbf, b * 1024 + tid * 4);
    } else if (b < 1024) {
        cvt4(Wo, wobf, (b - 768) * 1024 + tid * 4);
    } else if (b < 1120) {
        const int bb = b - 1024;
        const int batch = bb / 6;
        const int c = (bb % 6) * 256 + tid;
        const float4* a4 = (const float4*)(te + batch * 512);
        const float4* w4 = (const float4*)(Wt + (size_t)c * 512);
        float s = 0.f;
        for (int i = 0; i < 128; ++i) {
            float4 av = a4[i], wv = w4[i];
            s += av.x * wv.x + av.y * wv.y + av.z * wv.z + av.w * wv.w;
        }
        qkvt[batch * 1536 + c] = s + bt[c];
    } else if (b < 1152) {
        const int e0 = (b - 1120) * 1024 + tid;
        for (int k = 0; k < 4; ++k) {
            int e = e0 + k * 256;
            int h = e >> 12, rc = e & 4095, row = rc >> 6, col = rc & 63;
            int idx = ((row >> 3) - (col >> 3) + 7) * 15 + ((row & 7) - (col & 7) + 7);
            biasf[e] = btab[idx * 8 + h];
        }
    } else {
        const int base = (b - 1152) * 4096 + tid * 4;
        for (int k = 0; k < 4; ++k) cvt4(x, xbf, base + k * 1024);
    }
}

__global__ __launch_bounds__(256, 3) void gemm_qkv_k(
    const u16* __restrict__ A, const u16* __restrict__ B,
    const float* __restrict__ bqkv, const float* __restrict__ qkvt,
    u16* __restrict__ C)
{
    __shared__ __align__(16) u16 lA[128 * 32];
    __shared__ __align__(16) u16 lB[128 * 32];
    const int tid = threadIdx.x;
    const int lane = tid & 63, wv = tid >> 6;
    const int ln = lane & 15, quad = lane >> 4;

    const int orig = blockIdx.y * 12 + blockIdx.x;
    const int wgid = (orig & 7) * 768 + (orig >> 3);
    const int tm = wgid / 12, tn = wgid % 12;

    const int wm = (wv & 1) * 64, wn = (wv >> 1) * 64;

    floatx4 acc[4][4];
#pragma unroll
    for (int i = 0; i < 4; ++i)
#pragma unroll
        for (int j = 0; j < 4; ++j) acc[i][j] = (floatx4){0.f, 0.f, 0.f, 0.f};

    const int srow = tid >> 2, scb = tid & 3;
    const u16* ag = A + (size_t)(tm * 128 + srow) * 512 + scb * 8;
    const u16* bg = B + (size_t)(tn * 128 + srow) * 512 + scb * 8;
    u16* la0 = &lA[tid * 8];
    u16* la1 = &lA[2048 + tid * 8];
    u16* lb0 = &lB[tid * 8];
    u16* lb1 = &lB[2048 + tid * 8];

    for (int k0 = 0; k0 < 512; k0 += 32) {
        __syncthreads();
        gld16(ag + k0, la0);
        gld16(ag + 64 * 512 + k0, la1);
        gld16(bg + k0, lb0);
        gld16(bg + 64 * 512 + k0, lb1);
        __syncthreads();
        bf16x8 af[4], bf[4];
#pragma unroll
        for (int mt = 0; mt < 4; ++mt)
            af[mt] = *(const bf16x8*)&lA[(wm + mt * 16 + ln) * 32 + quad * 8];
#pragma unroll
        for (int nt = 0; nt < 4; ++nt)
            bf[nt] = *(const bf16x8*)&lB[(wn + nt * 16 + ln) * 32 + quad * 8];
#pragma unroll
        for (int mt = 0; mt < 4; ++mt)
#pragma unroll
            for (int nt = 0; nt < 4; ++nt)
                acc[mt][nt] = __builtin_amdgcn_mfma_f32_16x16x32_bf16(
                    af[mt], bf[nt], acc[mt][nt], 0, 0, 0);
    }

    const float* qt = qkvt + (tm >> 5) * 1536;
#pragma unroll
    for (int nt = 0; nt < 4; ++nt) {
        const int col = tn * 128 + wn + nt * 16 + ln;
        const float add = bqkv[col] + qt[col];
#pragma unroll
        for (int mt = 0; mt < 4; ++mt) {
            const int row0 = tm * 128 + wm + mt * 16 + quad * 4;
#pragma unroll
            for (int r = 0; r < 4; ++r)
                C[(size_t)(row0 + r) * 1536 + col] = f2bf(acc[mt][nt][r] + add);
        }
    }
}

__global__ __launch_bounds__(256, 4) void attn_k(
    const u16* __restrict__ qkv, const float* __restrict__ biasf,
    u16* __restrict__ aout)
{
    __shared__ __align__(16) u16 sbuf[4][64 * 72];
    const int tid = threadIdx.x, lane = tid & 63, wv = tid >> 6;
    const int ln = lane & 15, quad = lane >> 4;
    const int pair = blockIdx.x * 4 + wv;
    const int w = pair >> 3, h = pair & 7;
    const int bb = w >> 6, nh = (w >> 3) & 7, nw = w & 7;
    const int tbase = bb * 4096 + nh * 512 + nw * 8;
    u16* buf = sbuf[wv];

    {
        const int wj = lane >> 3;
        const int d0 = (lane & 7) * 8;
#pragma unroll
        for (int i = 0; i < 8; ++i) {
            const int t = tbase + i * 64 + wj;
            union { bf16x8 v; u16 u[8]; } cv;
            cv.v = *(const bf16x8*)(qkv + (size_t)t * 1536 + 1024 + h * 64 + d0);
            const int n = i * 8 + wj;
#pragma unroll
            for (int j = 0; j < 8; ++j) buf[(d0 + j) * 72 + n] = cv.u[j];
        }
    }

    bf16x8 vtf[4][2];
#pragma unroll
    for (int dt = 0; dt < 4; ++dt) {
        const u16* vr = &buf[(dt * 16 + ln) * 72 + quad * 8];
        vtf[dt][0] = *(const bf16x8*)vr;
        vtf[dt][1] = *(const bf16x8*)(vr + 32);
    }

    bf16x8 kf[4][2];
#pragma unroll
    for (int nt = 0; nt < 4; ++nt) {
        const int n = nt * 16 + ln;
        const int t = tbase + (n >> 3) * 64 + (n & 7);
        const u16* kr = qkv + (size_t)t * 1536 + 512 + h * 64 + quad * 8;
        kf[nt][0] = *(const bf16x8*)kr;
        kf[nt][1] = *(const bf16x8*)(kr + 32);
    }

#pragma unroll
    for (int mt = 0; mt < 4; ++mt) {
        const int m = mt * 16 + ln;
        const int t = tbase + (m >> 3) * 64 + (m & 7);
        const u16* qr = qkv + (size_t)t * 1536 + h * 64 + quad * 8;
        const bf16x8 qf0 = *(const bf16x8*)qr;
        const bf16x8 qf1 = *(const bf16x8*)(qr + 32);
        floatx4 s[4];
        __builtin_amdgcn_s_setprio(1);
#pragma unroll
        for (int nt = 0; nt < 4; ++nt) {
            s[nt] = (floatx4){0.f, 0.f, 0.f, 0.f};
            s[nt] = __builtin_amdgcn_mfma_f32_16x16x32_bf16(qf0, kf[nt][0], s[nt], 0, 0, 0);
            s[nt] = __builtin_amdgcn_mfma_f32_16x16x32_bf16(qf1, kf[nt][1], s[nt], 0, 0, 0);
        }
        __builtin_amdgcn_s_setprio(0);
        float z[4][4];
        const float* bptr = biasf + h * 4096 + (mt * 16 + quad * 4) * 64 + ln;
#pragma unroll
        for (int nt = 0; nt < 4; ++nt)
#pragma unroll
            for (int r = 0; r < 4; ++r)
                z[nt][r] = s[nt][r] * 0.125f + bptr[r * 64 + nt * 16];
        float pmax[4], prcp[4];
#pragma unroll
        for (int r = 0; r < 4; ++r) {
            float v = fmaxf(fmaxf(z[0][r], z[1][r]), fmaxf(z[2][r], z[3][r]));
            v = fmaxf(v, __shfl_xor(v, 1));
            v = fmaxf(v, __shfl_xor(v, 2));
            v = fmaxf(v, __shfl_xor(v, 4));
            v = fmaxf(v, __shfl_xor(v, 8));
            pmax[r] = v;
        }
#pragma unroll
        for (int nt = 0; nt < 4; ++nt)
#pragma unroll
            for (int r = 0; r < 4; ++r)
                z[nt][r] = __expf(z[nt][r] - pmax[r]);
#pragma unroll
        for (int r = 0; r < 4; ++r) {
            float v = z[0][r] + z[1][r] + z[2][r] + z[3][r];
            v += __shfl_xor(v, 1);
            v += __shfl_xor(v, 2);
            v += __shfl_xor(v, 4);
            v += __shfl_xor(v, 8);
            prcp[r] = __builtin_amdgcn_rcpf(v);
        }
#pragma unroll
        for (int nt = 0; nt < 4; ++nt)
#pragma unroll
            for (int r = 0; r < 4; ++r)
                buf[(mt * 16 + quad * 4 + r) * 72 + nt * 16 + ln] =
                    f2bf(z[nt][r] * prcp[r]);
    }

#pragma unroll
    for (int mt = 0; mt < 4; ++mt) {
        const u16* pr = &buf[(mt * 16 + ln) * 72 + quad * 8];
        const bf16x8 pf0 = *(const bf16x8*)pr;
        const bf16x8 pf1 = *(const bf16x8*)(pr + 32);
#pragma unroll
        for (int dt = 0; dt < 4; ++dt) {
            floatx4 o = (floatx4){0.f, 0.f, 0.f, 0.f};
            __builtin_amdgcn_s_setprio(1);
            o = __builtin_amdgcn_mfma_f32_16x16x32_bf16(pf0, vtf[dt][0], o, 0, 0, 0);
            o = __builtin_amdgcn_mfma_f32_16x16x32_bf16(pf1, vtf[dt][1], o, 0, 0, 0);
            __builtin_amdgcn_s_setprio(0);
            const size_t rbase =
                (size_t)(w * 64 + mt * 16 + quad * 4) * 512 + h * 64 + dt * 16 + ln;
#pragma unroll
            for (int r = 0; r < 4; ++r)
                aout[rbase + (size_t)r * 512] = f2bf(o[r]);
        }
    }
}

__global__ __launch_bounds__(256, 3) void gemm_out_k(
    const u16* __restrict__ A, const u16* __restrict__ B,
    const float* __restrict__ bo, float* __restrict__ C)
{
    __shared__ __align__(16) u16 lA[128 * 32];
    __shared__ __align__(16) u16 lB[128 * 32];
    const int tid = threadIdx.x;
    const int lane = tid & 63, wv = tid >> 6;
    const int ln = lane & 15, quad = lane >> 4;

    const int orig = blockIdx.y * 4 + blockIdx.x;
    const int wgid = (orig & 7) * 256 + (orig >> 3);
    const int tm = wgid >> 2, tn = wgid & 3;

    const int wm = (wv & 1) * 64, wn = (wv >> 1) * 64;

    floatx4 acc[4][4];
#pragma unroll
    for (int i = 0; i < 4; ++i)
#pragma unroll
        for (int j = 0; j < 4; ++j) acc[i][j] = (floatx4){0.f, 0.f, 0.f, 0.f};

    const int srow = tid >> 2, scb = tid & 3;
    const u16* ag = A + (size_t)(tm * 128 + srow) * 512 + scb * 8;
    const u16* bg = B + (size_t)(tn * 128 + srow) * 512 + scb * 8;
    u16* la0 = &lA[tid * 8];
    u16* la1 = &lA[2048 + tid * 8];
    u16* lb0 = &lB[tid * 8];
    u16* lb1 = &lB[2048 + tid * 8];

    for (int k0 = 0; k0 < 512; k0 += 32) {
        __syncthreads();
        gld16(ag + k0, la0);
        gld16(ag + 64 * 512 + k0, la1);
        gld16(bg + k0, lb0);
        gld16(bg + 64 * 512 + k0, lb1);
        __syncthreads();
        bf16x8 af[4], bf[4];
#pragma unroll
        for (int mt = 0; mt < 4; ++mt)
            af[mt] = *(const bf16x8*)&lA[(wm + mt * 16 + ln) * 32 + quad * 8];
#pragma unroll
        for (int nt = 0; nt < 4; ++nt)
            bf[nt] = *(const bf16x8*)&lB[(wn + nt * 16 + ln) * 32 + quad * 8];
#pragma unroll
        for (int mt = 0; mt < 4; ++mt)
#pragma unroll
            for (int nt = 0; nt < 4; ++nt)
                acc[mt][nt] = __builtin_amdgcn_mfma_f32_16x16x32_bf16(
                    af[mt], bf[nt], acc[mt][nt], 0, 0, 0);
    }

#pragma unroll
    for (int nt = 0; nt < 4; ++nt) {
        const int col = tn * 128 + wn + nt * 16 + ln;
        const float add = bo[col];
#pragma unroll
        for (int mt = 0; mt < 4; ++mt) {
            const int row0 = tm * 128 + wm + mt * 16 + quad * 4;
#pragma unroll
            for (int r = 0; r < 4; ++r)
                C[(size_t)(row0 + r) * 512 + col] = acc[mt][nt][r] + add;
        }
    }
}

// ---------- launch ----------
extern "C" void kernel_launch(void* const* d_in, const int* in_sizes, int n_in,
                              void* d_out, int out_size, void* d_ws, size_t ws_size,
                              hipStream_t stream)
{
    const float* x    = (const float*)d_in[0];
    const float* te   = (const float*)d_in[1];
    const float* Wqkv = (const float*)d_in[2];
    const float* bqkv = (const float*)d_in[3];
    const float* Wt   = (const float*)d_in[4];
    const float* bt   = (const float*)d_in[5];
    const float* Wo   = (const float*)d_in[6];
    const float* bo   = (const float*)d_in[7];
    const float* btab = (const float*)d_in[8];
    float* out = (float*)d_out;
    char* wsp  = (char*)d_ws;

    u16*   xbf    = (u16*)(wsp);
    u16*   qkvbf  = (u16*)(wsp + 67108864);
    u16*   wqkvbf = (u16*)(wsp + 268435456);
    u16*   wobf   = (u16*)(wsp + 270008320);
    float* qkvt   = (float*)(wsp + 270532608);
    float* biasf  = (float*)(wsp + 270630912);

    // one-time host-side capacity query (graph-capture-safe: no stream ops)
    static int coop_grid = -2;     // -2 unqueried | -1 disabled | >0 grid size
    if (coop_grid == -2) {
        int nb = 0;
        hipError_t e = hipOccupancyMaxActiveBlocksPerMultiprocessor(
            &nb, mega_k, 256, 0);
        if (e != hipSuccess || nb < 1) coop_grid = -1;
        else coop_grid = (nb >= 3) ? 768 : nb * 256;   // 256 CUs on MI355X
        (void)hipGetLastError();
    }

    if (coop_grid > 0) {
        void* args[] = {
            (void*)&x, (void*)&te, (void*)&Wqkv, (void*)&bqkv, (void*)&Wt,
            (void*)&bt, (void*)&Wo, (void*)&bo, (void*)&btab, (void*)&out,
            (void*)&wsp
        };
        hipError_t le = hipLaunchCooperativeKernel(
            (const void*)mega_k, dim3(coop_grid), dim3(256), args, 0, stream);
        if (le == hipSuccess) return;
        coop_grid = -1;            // latch fallback; never retry coop
        (void)hipGetLastError();
    }

    // fallback: round-5 verified 4-kernel path
    prep_k<<<9344, 256, 0, stream>>>(x, Wqkv, Wo, te, Wt, bt, btab,
                                     xbf, wqkvbf, wobf, qkvt, biasf);
    gemm_qkv_k<<<dim3(12, 512), 256, 0, stream>>>(xbf, wqkvbf, bqkv, qkvt, qkvbf);
    attn_k<<<2048, 256, 0, stream>>>(qkvbf, biasf, xbf);
    gemm_out_k<<<dim3(4, 512), 256, 0, stream>>>(xbf, wobf, bo, out);
}